// Round 1
// baseline (7559.074 us; speedup 1.0000x reference)
//
#include <hip/hip_runtime.h>
#include <hip/hip_bf16.h>

#define NN 100000
#define NE 1600000
#define HIDD 128
#define LDA 132   // 128 + 4 pad (keeps float4 alignment, breaks bank stride)

// ---------------------------------------------------------------------------
// Scatter-sum: agg[dst[e]][f] += X[src[e]][f], float4 per thread, atomics.
// grid = NE*32/256 blocks exactly.
__global__ __launch_bounds__(256) void scatter_kernel(
    const float* __restrict__ X, const int* __restrict__ src,
    const int* __restrict__ dst, float* __restrict__ agg)
{
    int gid = blockIdx.x * 256 + threadIdx.x;       // < NE*32 = 51.2M
    int e  = gid >> 5;
    int f  = (gid & 31) << 2;
    int s = src[e];
    int d = dst[e];
    const float4 v = *(const float4*)(X + (size_t)s * HIDD + f);
    float* o = agg + (size_t)d * HIDD + f;
    atomicAdd(o + 0, v.x);
    atomicAdd(o + 1, v.y);
    atomicAdd(o + 2, v.z);
    atomicAdd(o + 3, v.w);
}

// ---------------------------------------------------------------------------
// GEMM1: H = ((1+eps)*X + agg) @ W + b ; also accumulate per-column sum/sumsq
// of H into stats[0..127] / stats[128..255] (for BatchNorm batch stats).
// Block: 256 thr, tile 64 rows x 64 cols (blockIdx.y picks col half).
__global__ __launch_bounds__(256) void gemm_stats_kernel(
    const float* __restrict__ X, const float* __restrict__ agg,
    const float* __restrict__ epsp,
    const float* __restrict__ W, const float* __restrict__ bias,
    float* __restrict__ H, float* __restrict__ stats)
{
    __shared__ float As[64 * LDA];
    const int tid  = threadIdx.x;
    const int row0 = blockIdx.x * 64;
    const int c0   = blockIdx.y * 64;
    const float ep = 1.0f + epsp[0];

    // stage A = (1+eps)*X + agg  (64 rows x 128 k)
    #pragma unroll
    for (int p = 0; p < 8; ++p) {
        int idx = p * 256 + tid;
        int r   = idx >> 5;
        int k4  = (idx & 31) << 2;
        int row = row0 + r;
        float4 v = make_float4(0.f, 0.f, 0.f, 0.f);
        if (row < NN) {
            const float4 xv = *(const float4*)(X   + (size_t)row * HIDD + k4);
            const float4 av = *(const float4*)(agg + (size_t)row * HIDD + k4);
            v.x = fmaf(ep, xv.x, av.x);
            v.y = fmaf(ep, xv.y, av.y);
            v.z = fmaf(ep, xv.z, av.z);
            v.w = fmaf(ep, xv.w, av.w);
        }
        *(float4*)(&As[r * LDA + k4]) = v;
    }
    __syncthreads();

    const int tx = tid & 15;    // col quad
    const int ty = tid >> 4;    // row quad
    float acc[4][4] = {};

    const float* Wp = W + c0 + (tx << 2);
    #pragma unroll 4
    for (int k = 0; k < 128; ++k) {
        const float4 w4 = *(const float4*)(Wp + (size_t)k * HIDD);
        float a[4];
        #pragma unroll
        for (int i = 0; i < 4; ++i) a[i] = As[(ty * 4 + i) * LDA + k];
        #pragma unroll
        for (int i = 0; i < 4; ++i) {
            acc[i][0] = fmaf(a[i], w4.x, acc[i][0]);
            acc[i][1] = fmaf(a[i], w4.y, acc[i][1]);
            acc[i][2] = fmaf(a[i], w4.z, acc[i][2]);
            acc[i][3] = fmaf(a[i], w4.w, acc[i][3]);
        }
    }

    const float4 b4 = *(const float4*)(bias + c0 + (tx << 2));
    float psum[4] = {0.f, 0.f, 0.f, 0.f};
    float psq[4]  = {0.f, 0.f, 0.f, 0.f};
    #pragma unroll
    for (int i = 0; i < 4; ++i) {
        int row = row0 + ty * 4 + i;
        if (row < NN) {
            float4 h;
            h.x = acc[i][0] + b4.x;
            h.y = acc[i][1] + b4.y;
            h.z = acc[i][2] + b4.z;
            h.w = acc[i][3] + b4.w;
            *(float4*)(H + (size_t)row * HIDD + c0 + (tx << 2)) = h;
            psum[0] += h.x; psq[0] += h.x * h.x;
            psum[1] += h.y; psq[1] += h.y * h.y;
            psum[2] += h.z; psq[2] += h.z * h.z;
            psum[3] += h.w; psq[3] += h.w * h.w;
        }
    }
    // reduce over the 4 ty-groups inside each wave (lane bits 4,5), then atomics
    #pragma unroll
    for (int j = 0; j < 4; ++j) {
        float s = psum[j], q = psq[j];
        s += __shfl_xor(s, 16); q += __shfl_xor(q, 16);
        s += __shfl_xor(s, 32); q += __shfl_xor(q, 32);
        if ((tid & 48) == 0) {
            atomicAdd(&stats[c0 + (tx << 2) + j], s);
            atomicAdd(&stats[128 + c0 + (tx << 2) + j], q);
        }
    }
}

// ---------------------------------------------------------------------------
// Finalize BN: scale = g * 1/sqrt(var+eps), shift = beta - mu*scale
__global__ void finalize_kernel(float* __restrict__ stats,
                                const float* __restrict__ g,
                                const float* __restrict__ bt)
{
    int c = threadIdx.x;
    const float invN = 1.0f / (float)NN;
    float mu  = stats[c] * invN;
    float var = stats[128 + c] * invN - mu * mu;
    float rs  = 1.0f / sqrtf(var + 1e-5f);
    float sc  = g[c] * rs;
    stats[256 + c] = sc;
    stats[384 + c] = bt[c] - mu * sc;
}

// ---------------------------------------------------------------------------
// GEMM2: Y = relu_opt( relu(H*scale+shift) @ W + b )
__global__ __launch_bounds__(256) void gemm_post_kernel(
    const float* __restrict__ H, const float* __restrict__ stats,
    const float* __restrict__ W, const float* __restrict__ bias,
    float* __restrict__ Y, int final_relu)
{
    __shared__ float As[64 * LDA];
    const int tid  = threadIdx.x;
    const int row0 = blockIdx.x * 64;
    const int c0   = blockIdx.y * 64;

    #pragma unroll
    for (int p = 0; p < 8; ++p) {
        int idx = p * 256 + tid;
        int r   = idx >> 5;
        int k4  = (idx & 31) << 2;
        int row = row0 + r;
        float4 v = make_float4(0.f, 0.f, 0.f, 0.f);
        if (row < NN) {
            const float4 hv = *(const float4*)(H + (size_t)row * HIDD + k4);
            const float4 sc = *(const float4*)(stats + 256 + k4);
            const float4 sh = *(const float4*)(stats + 384 + k4);
            v.x = fmaxf(fmaf(hv.x, sc.x, sh.x), 0.f);
            v.y = fmaxf(fmaf(hv.y, sc.y, sh.y), 0.f);
            v.z = fmaxf(fmaf(hv.z, sc.z, sh.z), 0.f);
            v.w = fmaxf(fmaf(hv.w, sc.w, sh.w), 0.f);
        }
        *(float4*)(&As[r * LDA + k4]) = v;
    }
    __syncthreads();

    const int tx = tid & 15;
    const int ty = tid >> 4;
    float acc[4][4] = {};

    const float* Wp = W + c0 + (tx << 2);
    #pragma unroll 4
    for (int k = 0; k < 128; ++k) {
        const float4 w4 = *(const float4*)(Wp + (size_t)k * HIDD);
        float a[4];
        #pragma unroll
        for (int i = 0; i < 4; ++i) a[i] = As[(ty * 4 + i) * LDA + k];
        #pragma unroll
        for (int i = 0; i < 4; ++i) {
            acc[i][0] = fmaf(a[i], w4.x, acc[i][0]);
            acc[i][1] = fmaf(a[i], w4.y, acc[i][1]);
            acc[i][2] = fmaf(a[i], w4.z, acc[i][2]);
            acc[i][3] = fmaf(a[i], w4.w, acc[i][3]);
        }
    }

    const float4 b4 = *(const float4*)(bias + c0 + (tx << 2));
    #pragma unroll
    for (int i = 0; i < 4; ++i) {
        int row = row0 + ty * 4 + i;
        if (row < NN) {
            float4 h;
            h.x = acc[i][0] + b4.x;
            h.y = acc[i][1] + b4.y;
            h.z = acc[i][2] + b4.z;
            h.w = acc[i][3] + b4.w;
            if (final_relu) {
                h.x = fmaxf(h.x, 0.f);
                h.y = fmaxf(h.y, 0.f);
                h.z = fmaxf(h.z, 0.f);
                h.w = fmaxf(h.w, 0.f);
            }
            *(float4*)(Y + (size_t)row * HIDD + c0 + (tx << 2)) = h;
        }
    }
}

// ---------------------------------------------------------------------------
extern "C" void kernel_launch(void* const* d_in, const int* in_sizes, int n_in,
                              void* d_out, int out_size, void* d_ws, size_t ws_size,
                              hipStream_t stream)
{
    const float* x    = (const float*)d_in[0];
    const int*   src  = (const int*)  d_in[1];
    const int*   dst  = (const int*)  d_in[2];
    const float* eps1 = (const float*)d_in[3];
    const float* w1a  = (const float*)d_in[4];
    const float* b1a  = (const float*)d_in[5];
    const float* g1   = (const float*)d_in[6];
    const float* bt1  = (const float*)d_in[7];
    const float* w1b  = (const float*)d_in[8];
    const float* b1b  = (const float*)d_in[9];
    const float* eps2 = (const float*)d_in[10];
    const float* w2a  = (const float*)d_in[11];
    const float* b2a  = (const float*)d_in[12];
    const float* g2   = (const float*)d_in[13];
    const float* bt2  = (const float*)d_in[14];
    const float* w2b  = (const float*)d_in[15];
    const float* b2b  = (const float*)d_in[16];

    float* out   = (float*)d_out;
    float* agg   = (float*)d_ws;                       // N*128 f32 = 51.2 MB
    float* H     = agg + (size_t)NN * HIDD;            // N*128 f32 = 51.2 MB
    float* stats = H   + (size_t)NN * HIDD;            // 512 f32

    const int scatter_blocks = NE * 32 / 256;          // 200000
    dim3 gg((NN + 63) / 64, 2, 1);                     // (1563, 2)

    // ---- Layer 1 ----
    hipMemsetAsync(agg,   0, (size_t)NN * HIDD * sizeof(float), stream);
    hipMemsetAsync(stats, 0, 256 * sizeof(float), stream);
    scatter_kernel<<<scatter_blocks, 256, 0, stream>>>(x, src, dst, agg);
    gemm_stats_kernel<<<gg, 256, 0, stream>>>(x, agg, eps1, w1a, b1a, H, stats);
    finalize_kernel<<<1, 128, 0, stream>>>(stats, g1, bt1);
    gemm_post_kernel<<<gg, 256, 0, stream>>>(H, stats, w1b, b1b, out, 1);

    // ---- Layer 2 (input = out) ----
    hipMemsetAsync(agg,   0, (size_t)NN * HIDD * sizeof(float), stream);
    hipMemsetAsync(stats, 0, 256 * sizeof(float), stream);
    scatter_kernel<<<scatter_blocks, 256, 0, stream>>>(out, src, dst, agg);
    gemm_stats_kernel<<<gg, 256, 0, stream>>>(out, agg, eps2, w2a, b2a, H, stats);
    finalize_kernel<<<1, 128, 0, stream>>>(stats, g2, bt2);
    gemm_post_kernel<<<gg, 256, 0, stream>>>(H, stats, w2b, b2b, out, 0);
}

// Round 2
// 2888.847 us; speedup vs baseline: 2.6166x; 2.6166x over previous
//
#include <hip/hip_runtime.h>
#include <hip/hip_bf16.h>

#define NN 100000
#define NE 1600000
#define HIDD 128
#define LDA 132     // 128 + 4 pad
#define CHUNK 98    // ceil(NN / 1024)

// ---------------------------------------------------------------------------
// CSR build step 1: degree count (int atomics, 400KB L2-resident)
__global__ __launch_bounds__(256) void count_kernel(
    const int* __restrict__ dst, int* __restrict__ degcur)
{
    int e = blockIdx.x * 256 + threadIdx.x;   // grid sized exactly NE/256
    atomicAdd(&degcur[dst[e]], 1);
}

// ---------------------------------------------------------------------------
// CSR build step 2: single-block exclusive scan of degrees -> offs[NN+1],
// and re-init degcur as the running cursor (= exclusive prefix).
__global__ __launch_bounds__(1024) void scan_kernel(
    int* __restrict__ degcur, int* __restrict__ offs)
{
    __shared__ int sums[1024];
    const int t = threadIdx.x;
    const int beg = t * CHUNK;
    const int end = min(beg + CHUNK, NN);

    int s = 0;
    for (int i = beg; i < end; ++i) s += degcur[i];
    sums[t] = s;
    __syncthreads();

    // Hillis-Steele inclusive scan over 1024 partials
    for (int off = 1; off < 1024; off <<= 1) {
        int add = (t >= off) ? sums[t - off] : 0;
        __syncthreads();
        sums[t] += add;
        __syncthreads();
    }

    int p = sums[t] - s;   // exclusive prefix of this chunk
    for (int i = beg; i < end; ++i) {
        int d = degcur[i];
        offs[i]   = p;
        degcur[i] = p;     // cursor for fill phase
        p += d;
    }
    if (t == 1023) offs[NN] = sums[1023];   // == NE
}

// ---------------------------------------------------------------------------
// CSR build step 3: fill edge-source list grouped by dst
__global__ __launch_bounds__(256) void fill_kernel(
    const int* __restrict__ src, const int* __restrict__ dst,
    int* __restrict__ cursor, int* __restrict__ esrc)
{
    int e = blockIdx.x * 256 + threadIdx.x;
    int pos = atomicAdd(&cursor[dst[e]], 1);
    esrc[pos] = src[e];
}

// ---------------------------------------------------------------------------
// Gather + combine: A[n] = (1+eps)*X[n] + sum_{e: dst(e)=n} X[src(e)]
// One wave (64 lanes) per node; lane owns float2 of the 128 features.
__global__ __launch_bounds__(256) void gather_kernel(
    const float* __restrict__ X, const int* __restrict__ offs,
    const int* __restrict__ esrc, const float* __restrict__ epsp,
    float* __restrict__ A)
{
    const int gid  = blockIdx.x * 256 + threadIdx.x;
    const int n    = gid >> 6;
    const int lane = threadIdx.x & 63;
    if (n >= NN) return;

    const int beg = offs[n], end = offs[n + 1];
    const float ep = 1.0f + epsp[0];
    const size_t fo = (size_t)(lane << 1);

    float2 a0 = make_float2(0.f, 0.f), a1 = make_float2(0.f, 0.f);
    int i = beg;
    for (; i + 1 < end; i += 2) {
        int s0 = esrc[i], s1 = esrc[i + 1];
        const float2 v0 = *(const float2*)(X + (size_t)s0 * HIDD + fo);
        const float2 v1 = *(const float2*)(X + (size_t)s1 * HIDD + fo);
        a0.x += v0.x; a0.y += v0.y;
        a1.x += v1.x; a1.y += v1.y;
    }
    if (i < end) {
        int s = esrc[i];
        const float2 v = *(const float2*)(X + (size_t)s * HIDD + fo);
        a0.x += v.x; a0.y += v.y;
    }
    const float2 xv = *(const float2*)(X + (size_t)n * HIDD + fo);
    float2 o;
    o.x = fmaf(ep, xv.x, a0.x + a1.x);
    o.y = fmaf(ep, xv.y, a0.y + a1.y);
    *(float2*)(A + (size_t)n * HIDD + fo) = o;
}

// ---------------------------------------------------------------------------
// GEMM1: H = A @ W + b ; fused per-column sum/sumsq into stats (BN batch stats)
__global__ __launch_bounds__(256) void gemm_stats_kernel(
    const float* __restrict__ A_in,
    const float* __restrict__ W, const float* __restrict__ bias,
    float* __restrict__ H, float* __restrict__ stats)
{
    __shared__ float As[64 * LDA];
    const int tid  = threadIdx.x;
    const int row0 = blockIdx.x * 64;
    const int c0   = blockIdx.y * 64;

    #pragma unroll
    for (int p = 0; p < 8; ++p) {
        int idx = p * 256 + tid;
        int r   = idx >> 5;
        int k4  = (idx & 31) << 2;
        int row = row0 + r;
        float4 v = make_float4(0.f, 0.f, 0.f, 0.f);
        if (row < NN) v = *(const float4*)(A_in + (size_t)row * HIDD + k4);
        *(float4*)(&As[r * LDA + k4]) = v;
    }
    __syncthreads();

    const int tx = tid & 15;
    const int ty = tid >> 4;
    float acc[4][4] = {};

    const float* Wp = W + c0 + (tx << 2);
    #pragma unroll 4
    for (int k = 0; k < 128; ++k) {
        const float4 w4 = *(const float4*)(Wp + (size_t)k * HIDD);
        float a[4];
        #pragma unroll
        for (int i = 0; i < 4; ++i) a[i] = As[(ty * 4 + i) * LDA + k];
        #pragma unroll
        for (int i = 0; i < 4; ++i) {
            acc[i][0] = fmaf(a[i], w4.x, acc[i][0]);
            acc[i][1] = fmaf(a[i], w4.y, acc[i][1]);
            acc[i][2] = fmaf(a[i], w4.z, acc[i][2]);
            acc[i][3] = fmaf(a[i], w4.w, acc[i][3]);
        }
    }

    const float4 b4 = *(const float4*)(bias + c0 + (tx << 2));
    float psum[4] = {0.f, 0.f, 0.f, 0.f};
    float psq[4]  = {0.f, 0.f, 0.f, 0.f};
    #pragma unroll
    for (int i = 0; i < 4; ++i) {
        int row = row0 + ty * 4 + i;
        if (row < NN) {
            float4 h;
            h.x = acc[i][0] + b4.x;
            h.y = acc[i][1] + b4.y;
            h.z = acc[i][2] + b4.z;
            h.w = acc[i][3] + b4.w;
            *(float4*)(H + (size_t)row * HIDD + c0 + (tx << 2)) = h;
            psum[0] += h.x; psq[0] += h.x * h.x;
            psum[1] += h.y; psq[1] += h.y * h.y;
            psum[2] += h.z; psq[2] += h.z * h.z;
            psum[3] += h.w; psq[3] += h.w * h.w;
        }
    }
    #pragma unroll
    for (int j = 0; j < 4; ++j) {
        float s = psum[j], q = psq[j];
        s += __shfl_xor(s, 16); q += __shfl_xor(q, 16);
        s += __shfl_xor(s, 32); q += __shfl_xor(q, 32);
        if ((tid & 48) == 0) {
            atomicAdd(&stats[c0 + (tx << 2) + j], s);
            atomicAdd(&stats[128 + c0 + (tx << 2) + j], q);
        }
    }
}

// ---------------------------------------------------------------------------
__global__ void finalize_kernel(float* __restrict__ stats,
                                const float* __restrict__ g,
                                const float* __restrict__ bt)
{
    int c = threadIdx.x;
    const float invN = 1.0f / (float)NN;
    float mu  = stats[c] * invN;
    float var = stats[128 + c] * invN - mu * mu;
    float rs  = 1.0f / sqrtf(var + 1e-5f);
    float sc  = g[c] * rs;
    stats[256 + c] = sc;
    stats[384 + c] = bt[c] - mu * sc;
}

// ---------------------------------------------------------------------------
// GEMM2: Y = relu_opt( relu(H*scale+shift) @ W + b )
__global__ __launch_bounds__(256) void gemm_post_kernel(
    const float* __restrict__ H, const float* __restrict__ stats,
    const float* __restrict__ W, const float* __restrict__ bias,
    float* __restrict__ Y, int final_relu)
{
    __shared__ float As[64 * LDA];
    const int tid  = threadIdx.x;
    const int row0 = blockIdx.x * 64;
    const int c0   = blockIdx.y * 64;

    #pragma unroll
    for (int p = 0; p < 8; ++p) {
        int idx = p * 256 + tid;
        int r   = idx >> 5;
        int k4  = (idx & 31) << 2;
        int row = row0 + r;
        float4 v = make_float4(0.f, 0.f, 0.f, 0.f);
        if (row < NN) {
            const float4 hv = *(const float4*)(H + (size_t)row * HIDD + k4);
            const float4 sc = *(const float4*)(stats + 256 + k4);
            const float4 sh = *(const float4*)(stats + 384 + k4);
            v.x = fmaxf(fmaf(hv.x, sc.x, sh.x), 0.f);
            v.y = fmaxf(fmaf(hv.y, sc.y, sh.y), 0.f);
            v.z = fmaxf(fmaf(hv.z, sc.z, sh.z), 0.f);
            v.w = fmaxf(fmaf(hv.w, sc.w, sh.w), 0.f);
        }
        *(float4*)(&As[r * LDA + k4]) = v;
    }
    __syncthreads();

    const int tx = tid & 15;
    const int ty = tid >> 4;
    float acc[4][4] = {};

    const float* Wp = W + c0 + (tx << 2);
    #pragma unroll 4
    for (int k = 0; k < 128; ++k) {
        const float4 w4 = *(const float4*)(Wp + (size_t)k * HIDD);
        float a[4];
        #pragma unroll
        for (int i = 0; i < 4; ++i) a[i] = As[(ty * 4 + i) * LDA + k];
        #pragma unroll
        for (int i = 0; i < 4; ++i) {
            acc[i][0] = fmaf(a[i], w4.x, acc[i][0]);
            acc[i][1] = fmaf(a[i], w4.y, acc[i][1]);
            acc[i][2] = fmaf(a[i], w4.z, acc[i][2]);
            acc[i][3] = fmaf(a[i], w4.w, acc[i][3]);
        }
    }

    const float4 b4 = *(const float4*)(bias + c0 + (tx << 2));
    #pragma unroll
    for (int i = 0; i < 4; ++i) {
        int row = row0 + ty * 4 + i;
        if (row < NN) {
            float4 h;
            h.x = acc[i][0] + b4.x;
            h.y = acc[i][1] + b4.y;
            h.z = acc[i][2] + b4.z;
            h.w = acc[i][3] + b4.w;
            if (final_relu) {
                h.x = fmaxf(h.x, 0.f);
                h.y = fmaxf(h.y, 0.f);
                h.z = fmaxf(h.z, 0.f);
                h.w = fmaxf(h.w, 0.f);
            }
            *(float4*)(Y + (size_t)row * HIDD + c0 + (tx << 2)) = h;
        }
    }
}

// ---------------------------------------------------------------------------
extern "C" void kernel_launch(void* const* d_in, const int* in_sizes, int n_in,
                              void* d_out, int out_size, void* d_ws, size_t ws_size,
                              hipStream_t stream)
{
    const float* x    = (const float*)d_in[0];
    const int*   src  = (const int*)  d_in[1];
    const int*   dst  = (const int*)  d_in[2];
    const float* eps1 = (const float*)d_in[3];
    const float* w1a  = (const float*)d_in[4];
    const float* b1a  = (const float*)d_in[5];
    const float* g1   = (const float*)d_in[6];
    const float* bt1  = (const float*)d_in[7];
    const float* w1b  = (const float*)d_in[8];
    const float* b1b  = (const float*)d_in[9];
    const float* eps2 = (const float*)d_in[10];
    const float* w2a  = (const float*)d_in[11];
    const float* b2a  = (const float*)d_in[12];
    const float* g2   = (const float*)d_in[13];
    const float* bt2  = (const float*)d_in[14];
    const float* w2b  = (const float*)d_in[15];
    const float* b2b  = (const float*)d_in[16];

    float* out = (float*)d_out;

    // workspace layout
    float* A      = (float*)d_ws;                       // N*128 f32 = 51.2 MB
    float* H      = A + (size_t)NN * HIDD;              // N*128 f32 = 51.2 MB
    float* stats  = H + (size_t)NN * HIDD;              // 512 f32
    int*   offs   = (int*)(stats + 512);                // NN+1
    int*   degcur = offs + (NN + 1);                    // NN
    int*   esrc   = degcur + NN;                        // NE

    const int edge_blocks = NE / 256;                   // 6250
    const int gather_blocks = (NN * 64 + 255) / 256;    // 25000
    dim3 gg((NN + 63) / 64, 2, 1);                      // (1563, 2)

    // ---- CSR build (graph shared by both layers) ----
    hipMemsetAsync(degcur, 0, NN * sizeof(int), stream);
    count_kernel<<<edge_blocks, 256, 0, stream>>>(dst, degcur);
    scan_kernel<<<1, 1024, 0, stream>>>(degcur, offs);
    fill_kernel<<<edge_blocks, 256, 0, stream>>>(src, dst, degcur, esrc);

    // ---- Layer 1 ----
    hipMemsetAsync(stats, 0, 256 * sizeof(float), stream);
    gather_kernel<<<gather_blocks, 256, 0, stream>>>(x, offs, esrc, eps1, A);
    gemm_stats_kernel<<<gg, 256, 0, stream>>>(A, w1a, b1a, H, stats);
    finalize_kernel<<<1, 128, 0, stream>>>(stats, g1, bt1);
    gemm_post_kernel<<<gg, 256, 0, stream>>>(H, stats, w1b, b1b, out, 1);

    // ---- Layer 2 (input = out) ----
    hipMemsetAsync(stats, 0, 256 * sizeof(float), stream);
    gather_kernel<<<gather_blocks, 256, 0, stream>>>(out, offs, esrc, eps2, A);
    gemm_stats_kernel<<<gg, 256, 0, stream>>>(A, w2a, b2a, H, stats);
    finalize_kernel<<<1, 128, 0, stream>>>(stats, g2, bt2);
    gemm_post_kernel<<<gg, 256, 0, stream>>>(H, stats, w2b, b2b, out, 0);
}

// Round 4
// 1133.760 us; speedup vs baseline: 6.6673x; 2.5480x over previous
//
#include <hip/hip_runtime.h>
#include <hip/hip_bf16.h>

#define NN 100000
#define NE 1600000
#define HIDD 128
#define LDA 132     // 128 + 4 pad: 16B-aligned rows, 2-way-free LDS banks
#define CHUNK 98    // ceil(NN / 1024)
#define NB_X 1563   // ceil(NN / 64)

// ---------------------------------------------------------------------------
// CSR build step 1: degree count (int atomics, 400KB L2-resident)
__global__ __launch_bounds__(256) void count_kernel(
    const int* __restrict__ dst, int* __restrict__ degcur)
{
    int e = blockIdx.x * 256 + threadIdx.x;
    atomicAdd(&degcur[dst[e]], 1);
}

// ---------------------------------------------------------------------------
// CSR build step 2: single-block scan -> offs[NN+1]; degcur becomes cursor.
__global__ __launch_bounds__(1024) void scan_kernel(
    int* __restrict__ degcur, int* __restrict__ offs)
{
    __shared__ int sums[1024];
    const int t = threadIdx.x;
    const int beg = t * CHUNK;
    const int end = min(beg + CHUNK, NN);

    int s = 0;
    for (int i = beg; i < end; ++i) s += degcur[i];
    sums[t] = s;
    __syncthreads();

    for (int off = 1; off < 1024; off <<= 1) {
        int add = (t >= off) ? sums[t - off] : 0;
        __syncthreads();
        sums[t] += add;
        __syncthreads();
    }

    int p = sums[t] - s;
    for (int i = beg; i < end; ++i) {
        int d = degcur[i];
        offs[i]   = p;
        degcur[i] = p;
        p += d;
    }
    if (t == 1023) offs[NN] = sums[1023];
}

// ---------------------------------------------------------------------------
// CSR build step 3: fill edge-source list grouped by dst
__global__ __launch_bounds__(256) void fill_kernel(
    const int* __restrict__ src, const int* __restrict__ dst,
    int* __restrict__ cursor, int* __restrict__ esrc)
{
    int e = blockIdx.x * 256 + threadIdx.x;
    int pos = atomicAdd(&cursor[dst[e]], 1);
    esrc[pos] = src[e];
}

// ---------------------------------------------------------------------------
// Gather + combine: A[n] = (1+eps)*X[n] + sum_{e: dst(e)=n} X[src(e)]
__global__ __launch_bounds__(256) void gather_kernel(
    const float* __restrict__ X, const int* __restrict__ offs,
    const int* __restrict__ esrc, const float* __restrict__ epsp,
    float* __restrict__ A)
{
    const int gid  = blockIdx.x * 256 + threadIdx.x;
    const int n    = gid >> 6;
    const int lane = threadIdx.x & 63;
    if (n >= NN) return;

    const int beg = offs[n], end = offs[n + 1];
    const float ep = 1.0f + epsp[0];
    const size_t fo = (size_t)(lane << 1);

    float2 a0 = make_float2(0.f, 0.f), a1 = make_float2(0.f, 0.f);
    int i = beg;
    for (; i + 1 < end; i += 2) {
        int s0 = esrc[i], s1 = esrc[i + 1];
        const float2 v0 = *(const float2*)(X + (size_t)s0 * HIDD + fo);
        const float2 v1 = *(const float2*)(X + (size_t)s1 * HIDD + fo);
        a0.x += v0.x; a0.y += v0.y;
        a1.x += v1.x; a1.y += v1.y;
    }
    if (i < end) {
        int s = esrc[i];
        const float2 v = *(const float2*)(X + (size_t)s * HIDD + fo);
        a0.x += v.x; a0.y += v.y;
    }
    const float2 xv = *(const float2*)(X + (size_t)n * HIDD + fo);
    float2 o;
    o.x = fmaf(ep, xv.x, a0.x + a1.x);
    o.y = fmaf(ep, xv.y, a0.y + a1.y);
    *(float2*)(A + (size_t)n * HIDD + fo) = o;
}

// ---------------------------------------------------------------------------
// GEMM1: H = A @ W + b, per-block BN partials (NO global atomics).
// Block: 256 thr = 64 rows x 128 cols; thread tile 4 rows x 8 cols
// (cols 4tx..4tx+3 and 64+4tx..64+4tx+3 -> contiguous 256B per 16 lanes).
__global__ __launch_bounds__(256) void gemm_stats_kernel(
    const float* __restrict__ A_in,
    const float* __restrict__ W, const float* __restrict__ bias,
    float* __restrict__ H, float* __restrict__ partial)
{
    __shared__ float As[64 * LDA];
    __shared__ float sred[256];
    const int tid  = threadIdx.x;
    const int row0 = blockIdx.x * 64;

    #pragma unroll
    for (int p = 0; p < 8; ++p) {
        int idx = p * 256 + tid;
        int r   = idx >> 5;
        int k4  = (idx & 31) << 2;
        int row = row0 + r;
        float4 v = make_float4(0.f, 0.f, 0.f, 0.f);
        if (row < NN) v = *(const float4*)(A_in + (size_t)row * HIDD + k4);
        *(float4*)(&As[r * LDA + k4]) = v;
    }
    sred[tid] = 0.f;
    __syncthreads();

    const int tx = tid & 15;     // col group
    const int ty = tid >> 4;     // row group (0..15), rows 4ty..4ty+3
    float acc[4][8] = {};

    const float* Wp0 = W + (tx << 2);
    const float* Wp1 = W + 64 + (tx << 2);
    #pragma unroll 4
    for (int k = 0; k < 128; ++k) {
        const float4 w0 = *(const float4*)(Wp0 + (size_t)k * HIDD);
        const float4 w1 = *(const float4*)(Wp1 + (size_t)k * HIDD);
        float a[4];
        #pragma unroll
        for (int i = 0; i < 4; ++i) a[i] = As[(ty * 4 + i) * LDA + k];
        #pragma unroll
        for (int i = 0; i < 4; ++i) {
            acc[i][0] = fmaf(a[i], w0.x, acc[i][0]);
            acc[i][1] = fmaf(a[i], w0.y, acc[i][1]);
            acc[i][2] = fmaf(a[i], w0.z, acc[i][2]);
            acc[i][3] = fmaf(a[i], w0.w, acc[i][3]);
            acc[i][4] = fmaf(a[i], w1.x, acc[i][4]);
            acc[i][5] = fmaf(a[i], w1.y, acc[i][5]);
            acc[i][6] = fmaf(a[i], w1.z, acc[i][6]);
            acc[i][7] = fmaf(a[i], w1.w, acc[i][7]);
        }
    }

    const float4 b0 = *(const float4*)(bias + (tx << 2));
    const float4 b1 = *(const float4*)(bias + 64 + (tx << 2));
    float psum[8] = {}, psq[8] = {};
    #pragma unroll
    for (int i = 0; i < 4; ++i) {
        int row = row0 + ty * 4 + i;
        if (row < NN) {
            float h[8];
            h[0] = acc[i][0] + b0.x; h[1] = acc[i][1] + b0.y;
            h[2] = acc[i][2] + b0.z; h[3] = acc[i][3] + b0.w;
            h[4] = acc[i][4] + b1.x; h[5] = acc[i][5] + b1.y;
            h[6] = acc[i][6] + b1.z; h[7] = acc[i][7] + b1.w;
            *(float4*)(H + (size_t)row * HIDD + (tx << 2))      = make_float4(h[0], h[1], h[2], h[3]);
            *(float4*)(H + (size_t)row * HIDD + 64 + (tx << 2)) = make_float4(h[4], h[5], h[6], h[7]);
            #pragma unroll
            for (int j = 0; j < 8; ++j) { psum[j] += h[j]; psq[j] += h[j] * h[j]; }
        }
    }
    // reduce over the 4 row-groups within each wave (lane bits 4,5)
    #pragma unroll
    for (int j = 0; j < 8; ++j) {
        float s = psum[j], q = psq[j];
        s += __shfl_xor(s, 16); q += __shfl_xor(q, 16);
        s += __shfl_xor(s, 32); q += __shfl_xor(q, 32);
        if ((tid & 48) == 0) {
            int c = (j < 4) ? (tx << 2) + j : 64 + (tx << 2) + (j - 4);
            atomicAdd(&sred[c], s);          // LDS atomics only
            atomicAdd(&sred[128 + c], q);
        }
    }
    __syncthreads();
    partial[(size_t)blockIdx.x * 256 + tid] = sred[tid];
}

// ---------------------------------------------------------------------------
// Reduce per-block partials -> BN scale/shift (fuses old finalize_kernel).
__global__ __launch_bounds__(1024) void reduce_stats_kernel(
    const float* __restrict__ partial, const float* __restrict__ g,
    const float* __restrict__ bt, float* __restrict__ stats)
{
    __shared__ float buf[4][256];
    const int t  = threadIdx.x;
    const int c  = t & 255;
    const int ch = t >> 8;
    const int per = (NB_X + 3) / 4;
    const int b0 = ch * per;
    const int b1 = min(b0 + per, NB_X);

    float s = 0.f;
    #pragma unroll 8
    for (int b = b0; b < b1; ++b) s += partial[(size_t)b * 256 + c];
    buf[ch][c] = s;
    __syncthreads();

    if (t < 256) buf[0][t] = buf[0][t] + buf[1][t] + buf[2][t] + buf[3][t];
    __syncthreads();

    if (t < 128) {
        const float invN = 1.0f / (float)NN;
        float mu  = buf[0][t] * invN;
        float var = buf[0][128 + t] * invN - mu * mu;
        float sc  = g[t] * rsqrtf(var + 1e-5f);
        stats[256 + t] = sc;
        stats[384 + t] = bt[t] - mu * sc;
    }
}

// ---------------------------------------------------------------------------
// GEMM2: Y = relu_opt( relu(H*scale+shift) @ W + b )
__global__ __launch_bounds__(256) void gemm_post_kernel(
    const float* __restrict__ H, const float* __restrict__ stats,
    const float* __restrict__ W, const float* __restrict__ bias,
    float* __restrict__ Y, int final_relu)
{
    __shared__ float As[64 * LDA];
    const int tid  = threadIdx.x;
    const int row0 = blockIdx.x * 64;

    #pragma unroll
    for (int p = 0; p < 8; ++p) {
        int idx = p * 256 + tid;
        int r   = idx >> 5;
        int k4  = (idx & 31) << 2;
        int row = row0 + r;
        float4 v = make_float4(0.f, 0.f, 0.f, 0.f);
        if (row < NN) {
            const float4 hv = *(const float4*)(H + (size_t)row * HIDD + k4);
            const float4 sc = *(const float4*)(stats + 256 + k4);
            const float4 sh = *(const float4*)(stats + 384 + k4);
            v.x = fmaxf(fmaf(hv.x, sc.x, sh.x), 0.f);
            v.y = fmaxf(fmaf(hv.y, sc.y, sh.y), 0.f);
            v.z = fmaxf(fmaf(hv.z, sc.z, sh.z), 0.f);
            v.w = fmaxf(fmaf(hv.w, sc.w, sh.w), 0.f);
        }
        *(float4*)(&As[r * LDA + k4]) = v;
    }
    __syncthreads();

    const int tx = tid & 15;
    const int ty = tid >> 4;
    float acc[4][8] = {};

    const float* Wp0 = W + (tx << 2);
    const float* Wp1 = W + 64 + (tx << 2);
    #pragma unroll 4
    for (int k = 0; k < 128; ++k) {
        const float4 w0 = *(const float4*)(Wp0 + (size_t)k * HIDD);
        const float4 w1 = *(const float4*)(Wp1 + (size_t)k * HIDD);
        float a[4];
        #pragma unroll
        for (int i = 0; i < 4; ++i) a[i] = As[(ty * 4 + i) * LDA + k];
        #pragma unroll
        for (int i = 0; i < 4; ++i) {
            acc[i][0] = fmaf(a[i], w0.x, acc[i][0]);
            acc[i][1] = fmaf(a[i], w0.y, acc[i][1]);
            acc[i][2] = fmaf(a[i], w0.z, acc[i][2]);
            acc[i][3] = fmaf(a[i], w0.w, acc[i][3]);
            acc[i][4] = fmaf(a[i], w1.x, acc[i][4]);
            acc[i][5] = fmaf(a[i], w1.y, acc[i][5]);
            acc[i][6] = fmaf(a[i], w1.z, acc[i][6]);
            acc[i][7] = fmaf(a[i], w1.w, acc[i][7]);
        }
    }

    const float4 b0 = *(const float4*)(bias + (tx << 2));
    const float4 b1 = *(const float4*)(bias + 64 + (tx << 2));
    #pragma unroll
    for (int i = 0; i < 4; ++i) {
        int row = row0 + ty * 4 + i;
        if (row < NN) {
            float h[8];
            h[0] = acc[i][0] + b0.x; h[1] = acc[i][1] + b0.y;
            h[2] = acc[i][2] + b0.z; h[3] = acc[i][3] + b0.w;
            h[4] = acc[i][4] + b1.x; h[5] = acc[i][5] + b1.y;
            h[6] = acc[i][6] + b1.z; h[7] = acc[i][7] + b1.w;
            if (final_relu) {
                #pragma unroll
                for (int j = 0; j < 8; ++j) h[j] = fmaxf(h[j], 0.f);
            }
            *(float4*)(Y + (size_t)row * HIDD + (tx << 2))      = make_float4(h[0], h[1], h[2], h[3]);
            *(float4*)(Y + (size_t)row * HIDD + 64 + (tx << 2)) = make_float4(h[4], h[5], h[6], h[7]);
        }
    }
}

// ---------------------------------------------------------------------------
extern "C" void kernel_launch(void* const* d_in, const int* in_sizes, int n_in,
                              void* d_out, int out_size, void* d_ws, size_t ws_size,
                              hipStream_t stream)
{
    const float* x    = (const float*)d_in[0];
    const int*   src  = (const int*)  d_in[1];
    const int*   dst  = (const int*)  d_in[2];
    const float* eps1 = (const float*)d_in[3];
    const float* w1a  = (const float*)d_in[4];
    const float* b1a  = (const float*)d_in[5];
    const float* g1   = (const float*)d_in[6];
    const float* bt1  = (const float*)d_in[7];
    const float* w1b  = (const float*)d_in[8];
    const float* b1b  = (const float*)d_in[9];
    const float* eps2 = (const float*)d_in[10];
    const float* w2a  = (const float*)d_in[11];
    const float* b2a  = (const float*)d_in[12];
    const float* g2   = (const float*)d_in[13];
    const float* bt2  = (const float*)d_in[14];
    const float* w2b  = (const float*)d_in[15];
    const float* b2b  = (const float*)d_in[16];

    float* out = (float*)d_out;

    // workspace layout
    float* A       = (float*)d_ws;                      // N*128 f32 = 51.2 MB
    float* H       = A + (size_t)NN * HIDD;             // N*128 f32 = 51.2 MB
    float* stats   = H + (size_t)NN * HIDD;             // 512 f32
    float* partial = stats + 512;                       // NB_X*256 f32 = 1.6 MB
    int*   offs    = (int*)(partial + (size_t)NB_X * 256);  // NN+1
    int*   degcur  = offs + (NN + 1);                   // NN
    int*   esrc    = degcur + NN;                       // NE

    const int edge_blocks   = NE / 256;                 // 6250
    const int gather_blocks = (NN * 64 + 255) / 256;    // 25000

    // ---- CSR build (graph shared by both layers) ----
    hipMemsetAsync(degcur, 0, NN * sizeof(int), stream);
    count_kernel<<<edge_blocks, 256, 0, stream>>>(dst, degcur);
    scan_kernel<<<1, 1024, 0, stream>>>(degcur, offs);
    fill_kernel<<<edge_blocks, 256, 0, stream>>>(src, dst, degcur, esrc);

    // ---- Layer 1 ----
    gather_kernel<<<gather_blocks, 256, 0, stream>>>(x, offs, esrc, eps1, A);
    gemm_stats_kernel<<<NB_X, 256, 0, stream>>>(A, w1a, b1a, H, partial);
    reduce_stats_kernel<<<1, 1024, 0, stream>>>(partial, g1, bt1, stats);
    gemm_post_kernel<<<NB_X, 256, 0, stream>>>(H, stats, w1b, b1b, out, 1);

    // ---- Layer 2 (input = out) ----
    gather_kernel<<<gather_blocks, 256, 0, stream>>>(out, offs, esrc, eps2, A);
    gemm_stats_kernel<<<NB_X, 256, 0, stream>>>(A, w2a, b2a, H, partial);
    reduce_stats_kernel<<<1, 1024, 0, stream>>>(partial, g2, bt2, stats);
    gemm_post_kernel<<<NB_X, 256, 0, stream>>>(H, stats, w2b, b2b, out, 0);
}

// Round 5
// 858.899 us; speedup vs baseline: 8.8009x; 1.3200x over previous
//
#include <hip/hip_runtime.h>
#include <hip/hip_bf16.h>

#define NN 100000
#define NE 1600000
#define HIDD 128
#define LDA 132     // 128 + 4 pad: 16B-aligned rows, 2-way-free LDS banks
#define NB_X 1563   // ceil(NN / 64)
#define NSB 98      // ceil(NN / 1024) scan blocks

// ---------------------------------------------------------------------------
// CSR build step 1: degree count (int atomics, 400KB L2-resident)
__global__ __launch_bounds__(256) void count_kernel(
    const int* __restrict__ dst, int* __restrict__ degcur)
{
    int e = blockIdx.x * 256 + threadIdx.x;
    atomicAdd(&degcur[dst[e]], 1);
}

// ---------------------------------------------------------------------------
// Scan phase 1: per-block (1024 elems) exclusive scan via wave shfl + LDS,
// emit block-local exclusive values + per-block total.
__global__ __launch_bounds__(1024) void scan1_kernel(
    const int* __restrict__ deg, int* __restrict__ scanned,
    int* __restrict__ bsum)
{
    const int t    = threadIdx.x;
    const int i    = blockIdx.x * 1024 + t;
    const int lane = t & 63;
    const int w    = t >> 6;

    int v = (i < NN) ? deg[i] : 0;
    int x = v;
    // inclusive scan within wave
    #pragma unroll
    for (int off = 1; off < 64; off <<= 1) {
        int y = __shfl_up(x, off);
        if (lane >= off) x += y;
    }
    __shared__ int wsum[16];
    if (lane == 63) wsum[w] = x;
    __syncthreads();
    if (w == 0) {
        int s = (lane < 16) ? wsum[lane] : 0;
        #pragma unroll
        for (int off = 1; off < 16; off <<= 1) {
            int y = __shfl_up(s, off);
            if (lane >= off) s += y;
        }
        if (lane < 16) wsum[lane] = s;   // inclusive wave sums
    }
    __syncthreads();
    int base = (w > 0) ? wsum[w - 1] : 0;
    int incl = base + x;
    scanned[i] = incl - v;               // block-local exclusive
    if (t == 1023) bsum[blockIdx.x] = incl;
}

// ---------------------------------------------------------------------------
// Scan phase 2: scan the NSB block totals -> exclusive block bases.
__global__ __launch_bounds__(128) void scan2_kernel(
    const int* __restrict__ bsum, int* __restrict__ bbase,
    int* __restrict__ offs)
{
    __shared__ int sh[128];
    const int t = threadIdx.x;
    int v = (t < NSB) ? bsum[t] : 0;
    sh[t] = v;
    __syncthreads();
    for (int off = 1; off < 128; off <<= 1) {
        int add = (t >= off) ? sh[t - off] : 0;
        __syncthreads();
        sh[t] += add;
        __syncthreads();
    }
    if (t < NSB) bbase[t] = sh[t] - v;   // exclusive
    if (t == NSB - 1) offs[NN] = sh[t];  // total == NE
}

// ---------------------------------------------------------------------------
// Scan phase 3: final offsets = block-local + block base; init fill cursor.
__global__ __launch_bounds__(1024) void scan3_kernel(
    const int* __restrict__ scanned, const int* __restrict__ bbase,
    int* __restrict__ offs, int* __restrict__ cursor)
{
    int i = blockIdx.x * 1024 + threadIdx.x;
    if (i < NN) {
        int o = scanned[i] + bbase[blockIdx.x];
        offs[i]   = o;
        cursor[i] = o;
    }
}

// ---------------------------------------------------------------------------
// CSR build step 3: fill edge-source list grouped by dst
__global__ __launch_bounds__(256) void fill_kernel(
    const int* __restrict__ src, const int* __restrict__ dst,
    int* __restrict__ cursor, int* __restrict__ esrc)
{
    int e = blockIdx.x * 256 + threadIdx.x;
    int pos = atomicAdd(&cursor[dst[e]], 1);
    esrc[pos] = src[e];
}

// ---------------------------------------------------------------------------
// Gather + combine: A[n] = (1+eps)*X[n] + sum_{e: dst(e)=n} X[src(e)]
// One wave per node, lane owns float2; 4-wide edge unroll for MLP.
__global__ __launch_bounds__(256) void gather_kernel(
    const float* __restrict__ X, const int* __restrict__ offs,
    const int* __restrict__ esrc, const float* __restrict__ epsp,
    float* __restrict__ A)
{
    const int gid  = blockIdx.x * 256 + threadIdx.x;
    const int n    = gid >> 6;
    const int lane = threadIdx.x & 63;
    if (n >= NN) return;

    const int beg = offs[n], end = offs[n + 1];
    const float ep = 1.0f + epsp[0];
    const size_t fo = (size_t)(lane << 1);

    float2 a0 = make_float2(0.f, 0.f), a1 = make_float2(0.f, 0.f);
    float2 a2 = make_float2(0.f, 0.f), a3 = make_float2(0.f, 0.f);
    int i = beg;
    for (; i + 3 < end; i += 4) {
        int s0 = esrc[i], s1 = esrc[i + 1], s2 = esrc[i + 2], s3 = esrc[i + 3];
        const float2 v0 = *(const float2*)(X + (size_t)s0 * HIDD + fo);
        const float2 v1 = *(const float2*)(X + (size_t)s1 * HIDD + fo);
        const float2 v2 = *(const float2*)(X + (size_t)s2 * HIDD + fo);
        const float2 v3 = *(const float2*)(X + (size_t)s3 * HIDD + fo);
        a0.x += v0.x; a0.y += v0.y;
        a1.x += v1.x; a1.y += v1.y;
        a2.x += v2.x; a2.y += v2.y;
        a3.x += v3.x; a3.y += v3.y;
    }
    for (; i < end; ++i) {
        int s = esrc[i];
        const float2 v = *(const float2*)(X + (size_t)s * HIDD + fo);
        a0.x += v.x; a0.y += v.y;
    }
    const float2 xv = *(const float2*)(X + (size_t)n * HIDD + fo);
    float2 o;
    o.x = fmaf(ep, xv.x, (a0.x + a1.x) + (a2.x + a3.x));
    o.y = fmaf(ep, xv.y, (a0.y + a1.y) + (a2.y + a3.y));
    *(float2*)(A + (size_t)n * HIDD + fo) = o;
}

// ---------------------------------------------------------------------------
// GEMM1: H = A @ W + b, per-block BN partials (NO global atomics).
__global__ __launch_bounds__(256) void gemm_stats_kernel(
    const float* __restrict__ A_in,
    const float* __restrict__ W, const float* __restrict__ bias,
    float* __restrict__ H, float* __restrict__ partial)
{
    __shared__ float As[64 * LDA];
    __shared__ float sred[256];
    const int tid  = threadIdx.x;
    const int row0 = blockIdx.x * 64;

    #pragma unroll
    for (int p = 0; p < 8; ++p) {
        int idx = p * 256 + tid;
        int r   = idx >> 5;
        int k4  = (idx & 31) << 2;
        int row = row0 + r;
        float4 v = make_float4(0.f, 0.f, 0.f, 0.f);
        if (row < NN) v = *(const float4*)(A_in + (size_t)row * HIDD + k4);
        *(float4*)(&As[r * LDA + k4]) = v;
    }
    sred[tid] = 0.f;
    __syncthreads();

    const int tx = tid & 15;
    const int ty = tid >> 4;
    float acc[4][8] = {};

    const float* Wp0 = W + (tx << 2);
    const float* Wp1 = W + 64 + (tx << 2);
    #pragma unroll 4
    for (int k = 0; k < 128; ++k) {
        const float4 w0 = *(const float4*)(Wp0 + (size_t)k * HIDD);
        const float4 w1 = *(const float4*)(Wp1 + (size_t)k * HIDD);
        float a[4];
        #pragma unroll
        for (int i = 0; i < 4; ++i) a[i] = As[(ty * 4 + i) * LDA + k];
        #pragma unroll
        for (int i = 0; i < 4; ++i) {
            acc[i][0] = fmaf(a[i], w0.x, acc[i][0]);
            acc[i][1] = fmaf(a[i], w0.y, acc[i][1]);
            acc[i][2] = fmaf(a[i], w0.z, acc[i][2]);
            acc[i][3] = fmaf(a[i], w0.w, acc[i][3]);
            acc[i][4] = fmaf(a[i], w1.x, acc[i][4]);
            acc[i][5] = fmaf(a[i], w1.y, acc[i][5]);
            acc[i][6] = fmaf(a[i], w1.z, acc[i][6]);
            acc[i][7] = fmaf(a[i], w1.w, acc[i][7]);
        }
    }

    const float4 b0 = *(const float4*)(bias + (tx << 2));
    const float4 b1 = *(const float4*)(bias + 64 + (tx << 2));
    float psum[8] = {}, psq[8] = {};
    #pragma unroll
    for (int i = 0; i < 4; ++i) {
        int row = row0 + ty * 4 + i;
        if (row < NN) {
            float h[8];
            h[0] = acc[i][0] + b0.x; h[1] = acc[i][1] + b0.y;
            h[2] = acc[i][2] + b0.z; h[3] = acc[i][3] + b0.w;
            h[4] = acc[i][4] + b1.x; h[5] = acc[i][5] + b1.y;
            h[6] = acc[i][6] + b1.z; h[7] = acc[i][7] + b1.w;
            *(float4*)(H + (size_t)row * HIDD + (tx << 2))      = make_float4(h[0], h[1], h[2], h[3]);
            *(float4*)(H + (size_t)row * HIDD + 64 + (tx << 2)) = make_float4(h[4], h[5], h[6], h[7]);
            #pragma unroll
            for (int j = 0; j < 8; ++j) { psum[j] += h[j]; psq[j] += h[j] * h[j]; }
        }
    }
    #pragma unroll
    for (int j = 0; j < 8; ++j) {
        float s = psum[j], q = psq[j];
        s += __shfl_xor(s, 16); q += __shfl_xor(q, 16);
        s += __shfl_xor(s, 32); q += __shfl_xor(q, 32);
        if ((tid & 48) == 0) {
            int c = (j < 4) ? (tx << 2) + j : 64 + (tx << 2) + (j - 4);
            atomicAdd(&sred[c], s);          // LDS atomics only
            atomicAdd(&sred[128 + c], q);
        }
    }
    __syncthreads();
    partial[(size_t)blockIdx.x * 256 + tid] = sred[tid];
}

// ---------------------------------------------------------------------------
// Reduce per-block partials -> BN scale/shift.
__global__ __launch_bounds__(1024) void reduce_stats_kernel(
    const float* __restrict__ partial, const float* __restrict__ g,
    const float* __restrict__ bt, float* __restrict__ stats)
{
    __shared__ float buf[4][256];
    const int t  = threadIdx.x;
    const int c  = t & 255;
    const int ch = t >> 8;
    const int per = (NB_X + 3) / 4;
    const int b0 = ch * per;
    const int b1 = min(b0 + per, NB_X);

    float s = 0.f;
    #pragma unroll 8
    for (int b = b0; b < b1; ++b) s += partial[(size_t)b * 256 + c];
    buf[ch][c] = s;
    __syncthreads();

    if (t < 256) buf[0][t] = buf[0][t] + buf[1][t] + buf[2][t] + buf[3][t];
    __syncthreads();

    if (t < 128) {
        const float invN = 1.0f / (float)NN;
        float mu  = buf[0][t] * invN;
        float var = buf[0][128 + t] * invN - mu * mu;
        float sc  = g[t] * rsqrtf(var + 1e-5f);
        stats[256 + t] = sc;
        stats[384 + t] = bt[t] - mu * sc;
    }
}

// ---------------------------------------------------------------------------
// GEMM2: Y = relu_opt( relu(H*scale+shift) @ W + b )
__global__ __launch_bounds__(256) void gemm_post_kernel(
    const float* __restrict__ H, const float* __restrict__ stats,
    const float* __restrict__ W, const float* __restrict__ bias,
    float* __restrict__ Y, int final_relu)
{
    __shared__ float As[64 * LDA];
    const int tid  = threadIdx.x;
    const int row0 = blockIdx.x * 64;

    #pragma unroll
    for (int p = 0; p < 8; ++p) {
        int idx = p * 256 + tid;
        int r   = idx >> 5;
        int k4  = (idx & 31) << 2;
        int row = row0 + r;
        float4 v = make_float4(0.f, 0.f, 0.f, 0.f);
        if (row < NN) {
            const float4 hv = *(const float4*)(H + (size_t)row * HIDD + k4);
            const float4 sc = *(const float4*)(stats + 256 + k4);
            const float4 sh = *(const float4*)(stats + 384 + k4);
            v.x = fmaxf(fmaf(hv.x, sc.x, sh.x), 0.f);
            v.y = fmaxf(fmaf(hv.y, sc.y, sh.y), 0.f);
            v.z = fmaxf(fmaf(hv.z, sc.z, sh.z), 0.f);
            v.w = fmaxf(fmaf(hv.w, sc.w, sh.w), 0.f);
        }
        *(float4*)(&As[r * LDA + k4]) = v;
    }
    __syncthreads();

    const int tx = tid & 15;
    const int ty = tid >> 4;
    float acc[4][8] = {};

    const float* Wp0 = W + (tx << 2);
    const float* Wp1 = W + 64 + (tx << 2);
    #pragma unroll 4
    for (int k = 0; k < 128; ++k) {
        const float4 w0 = *(const float4*)(Wp0 + (size_t)k * HIDD);
        const float4 w1 = *(const float4*)(Wp1 + (size_t)k * HIDD);
        float a[4];
        #pragma unroll
        for (int i = 0; i < 4; ++i) a[i] = As[(ty * 4 + i) * LDA + k];
        #pragma unroll
        for (int i = 0; i < 4; ++i) {
            acc[i][0] = fmaf(a[i], w0.x, acc[i][0]);
            acc[i][1] = fmaf(a[i], w0.y, acc[i][1]);
            acc[i][2] = fmaf(a[i], w0.z, acc[i][2]);
            acc[i][3] = fmaf(a[i], w0.w, acc[i][3]);
            acc[i][4] = fmaf(a[i], w1.x, acc[i][4]);
            acc[i][5] = fmaf(a[i], w1.y, acc[i][5]);
            acc[i][6] = fmaf(a[i], w1.z, acc[i][6]);
            acc[i][7] = fmaf(a[i], w1.w, acc[i][7]);
        }
    }

    const float4 b0 = *(const float4*)(bias + (tx << 2));
    const float4 b1 = *(const float4*)(bias + 64 + (tx << 2));
    #pragma unroll
    for (int i = 0; i < 4; ++i) {
        int row = row0 + ty * 4 + i;
        if (row < NN) {
            float h[8];
            h[0] = acc[i][0] + b0.x; h[1] = acc[i][1] + b0.y;
            h[2] = acc[i][2] + b0.z; h[3] = acc[i][3] + b0.w;
            h[4] = acc[i][4] + b1.x; h[5] = acc[i][5] + b1.y;
            h[6] = acc[i][6] + b1.z; h[7] = acc[i][7] + b1.w;
            if (final_relu) {
                #pragma unroll
                for (int j = 0; j < 8; ++j) h[j] = fmaxf(h[j], 0.f);
            }
            *(float4*)(Y + (size_t)row * HIDD + (tx << 2))      = make_float4(h[0], h[1], h[2], h[3]);
            *(float4*)(Y + (size_t)row * HIDD + 64 + (tx << 2)) = make_float4(h[4], h[5], h[6], h[7]);
        }
    }
}

// ---------------------------------------------------------------------------
extern "C" void kernel_launch(void* const* d_in, const int* in_sizes, int n_in,
                              void* d_out, int out_size, void* d_ws, size_t ws_size,
                              hipStream_t stream)
{
    const float* x    = (const float*)d_in[0];
    const int*   src  = (const int*)  d_in[1];
    const int*   dst  = (const int*)  d_in[2];
    const float* eps1 = (const float*)d_in[3];
    const float* w1a  = (const float*)d_in[4];
    const float* b1a  = (const float*)d_in[5];
    const float* g1   = (const float*)d_in[6];
    const float* bt1  = (const float*)d_in[7];
    const float* w1b  = (const float*)d_in[8];
    const float* b1b  = (const float*)d_in[9];
    const float* eps2 = (const float*)d_in[10];
    const float* w2a  = (const float*)d_in[11];
    const float* b2a  = (const float*)d_in[12];
    const float* g2   = (const float*)d_in[13];
    const float* bt2  = (const float*)d_in[14];
    const float* w2b  = (const float*)d_in[15];
    const float* b2b  = (const float*)d_in[16];

    float* out = (float*)d_out;

    // workspace layout
    float* A       = (float*)d_ws;                      // N*128 f32 = 51.2 MB
    float* H       = A + (size_t)NN * HIDD;             // N*128 f32 = 51.2 MB
    float* stats   = H + (size_t)NN * HIDD;             // 512 f32
    float* partial = stats + 512;                       // NB_X*256 f32 = 1.6 MB
    int*   offs    = (int*)(partial + (size_t)NB_X * 256);  // NN+1
    int*   degcur  = offs + (NN + 1);                   // NN (deg, then cursor)
    int*   esrc    = degcur + NN;                       // NE
    int*   scanned = esrc + NE;                         // NSB*1024
    int*   bsum    = scanned + NSB * 1024;              // NSB
    int*   bbase   = bsum + NSB;                        // NSB

    const int edge_blocks   = NE / 256;                 // 6250
    const int gather_blocks = (NN * 64 + 255) / 256;    // 25000

    // ---- CSR build (graph shared by both layers) ----
    hipMemsetAsync(degcur, 0, NN * sizeof(int), stream);
    count_kernel<<<edge_blocks, 256, 0, stream>>>(dst, degcur);
    scan1_kernel<<<NSB, 1024, 0, stream>>>(degcur, scanned, bsum);
    scan2_kernel<<<1, 128, 0, stream>>>(bsum, bbase, offs);
    scan3_kernel<<<NSB, 1024, 0, stream>>>(scanned, bbase, offs, degcur);
    fill_kernel<<<edge_blocks, 256, 0, stream>>>(src, dst, degcur, esrc);

    // ---- Layer 1 ----
    gather_kernel<<<gather_blocks, 256, 0, stream>>>(x, offs, esrc, eps1, A);
    gemm_stats_kernel<<<NB_X, 256, 0, stream>>>(A, w1a, b1a, H, partial);
    reduce_stats_kernel<<<1, 1024, 0, stream>>>(partial, g1, bt1, stats);
    gemm_post_kernel<<<NB_X, 256, 0, stream>>>(H, stats, w1b, b1b, out, 1);

    // ---- Layer 2 (input = out) ----
    gather_kernel<<<gather_blocks, 256, 0, stream>>>(out, offs, esrc, eps2, A);
    gemm_stats_kernel<<<NB_X, 256, 0, stream>>>(A, w2a, b2a, H, partial);
    reduce_stats_kernel<<<1, 1024, 0, stream>>>(partial, g2, bt2, stats);
    gemm_post_kernel<<<NB_X, 256, 0, stream>>>(H, stats, w2b, b2b, out, 0);
}

// Round 6
// 726.096 us; speedup vs baseline: 10.4106x; 1.1829x over previous
//
#include <hip/hip_runtime.h>
#include <hip/hip_bf16.h>

#define NN 100000
#define NE 1600000
#define HIDD 128
#define NB_X 1563   // ceil(NN / 64)
#define NSB 98      // ceil(NN / 1024) scan blocks
#define LDAS 136    // A-tile LDS row stride in bf16 (272 B -> 2-way conflict, free)

typedef short short8 __attribute__((ext_vector_type(8)));
typedef float f32x4 __attribute__((ext_vector_type(4)));

__device__ inline short f2bf(float f) {
    union { float f; unsigned int u; } v; v.f = f;
    unsigned int u = v.u + 0x7FFF + ((v.u >> 16) & 1);   // RNE
    return (short)(u >> 16);
}
__device__ inline float bf2f(short s) {
    union { unsigned int u; float f; } v; v.u = ((unsigned int)(unsigned short)s) << 16;
    return v.f;
}

// ---------------------------------------------------------------------------
// CSR build step 1: degree count (int atomics, 400KB L2-resident)
__global__ __launch_bounds__(256) void count_kernel(
    const int* __restrict__ dst, int* __restrict__ degcur)
{
    int e = blockIdx.x * 256 + threadIdx.x;
    atomicAdd(&degcur[dst[e]], 1);
}

// ---------------------------------------------------------------------------
// Scan phase 1: per-block (1024 elems) scan via wave shfl + LDS
__global__ __launch_bounds__(1024) void scan1_kernel(
    const int* __restrict__ deg, int* __restrict__ scanned,
    int* __restrict__ bsum)
{
    const int t    = threadIdx.x;
    const int i    = blockIdx.x * 1024 + t;
    const int lane = t & 63;
    const int w    = t >> 6;

    int v = (i < NN) ? deg[i] : 0;
    int x = v;
    #pragma unroll
    for (int off = 1; off < 64; off <<= 1) {
        int y = __shfl_up(x, off);
        if (lane >= off) x += y;
    }
    __shared__ int wsum[16];
    if (lane == 63) wsum[w] = x;
    __syncthreads();
    if (w == 0) {
        int s = (lane < 16) ? wsum[lane] : 0;
        #pragma unroll
        for (int off = 1; off < 16; off <<= 1) {
            int y = __shfl_up(s, off);
            if (lane >= off) s += y;
        }
        if (lane < 16) wsum[lane] = s;
    }
    __syncthreads();
    int base = (w > 0) ? wsum[w - 1] : 0;
    int incl = base + x;
    scanned[i] = incl - v;
    if (t == 1023) bsum[blockIdx.x] = incl;
}

// ---------------------------------------------------------------------------
__global__ __launch_bounds__(128) void scan2_kernel(
    const int* __restrict__ bsum, int* __restrict__ bbase,
    int* __restrict__ offs)
{
    __shared__ int sh[128];
    const int t = threadIdx.x;
    int v = (t < NSB) ? bsum[t] : 0;
    sh[t] = v;
    __syncthreads();
    for (int off = 1; off < 128; off <<= 1) {
        int add = (t >= off) ? sh[t - off] : 0;
        __syncthreads();
        sh[t] += add;
        __syncthreads();
    }
    if (t < NSB) bbase[t] = sh[t] - v;
    if (t == NSB - 1) offs[NN] = sh[t];
}

// ---------------------------------------------------------------------------
__global__ __launch_bounds__(1024) void scan3_kernel(
    const int* __restrict__ scanned, const int* __restrict__ bbase,
    int* __restrict__ offs, int* __restrict__ cursor)
{
    int i = blockIdx.x * 1024 + threadIdx.x;
    if (i < NN) {
        int o = scanned[i] + bbase[blockIdx.x];
        offs[i]   = o;
        cursor[i] = o;
    }
}

// ---------------------------------------------------------------------------
__global__ __launch_bounds__(256) void fill_kernel(
    const int* __restrict__ src, const int* __restrict__ dst,
    int* __restrict__ cursor, int* __restrict__ esrc)
{
    int e = blockIdx.x * 256 + threadIdx.x;
    int pos = atomicAdd(&cursor[dst[e]], 1);
    esrc[pos] = src[e];
}

// ---------------------------------------------------------------------------
// Convert 4 weight matrices f32[k][n] -> bf16 transposed wt[n][k]
__global__ __launch_bounds__(256) void convert_w_kernel(
    const float* __restrict__ w0, const float* __restrict__ w1,
    const float* __restrict__ w2, const float* __restrict__ w3,
    short* __restrict__ wt)
{
    const float* wsrc = (blockIdx.x == 0) ? w0 : (blockIdx.x == 1) ? w1
                      : (blockIdx.x == 2) ? w2 : w3;
    short* o = wt + blockIdx.x * 16384;
    for (int p = 0; p < 64; ++p) {
        int idx = p * 256 + threadIdx.x;
        int n = idx >> 7, k = idx & 127;
        o[n * 128 + k] = f2bf(wsrc[k * 128 + n]);
    }
}

// ---------------------------------------------------------------------------
// Gather + combine -> bf16 A: A[n] = bf16((1+eps)*X[n] + sum X[src(e)])
__global__ __launch_bounds__(256) void gather_kernel(
    const float* __restrict__ X, const int* __restrict__ offs,
    const int* __restrict__ esrc, const float* __restrict__ epsp,
    unsigned int* __restrict__ Ab)   // packed 2x bf16 per uint
{
    const int gid  = blockIdx.x * 256 + threadIdx.x;
    const int n    = gid >> 6;
    const int lane = threadIdx.x & 63;
    if (n >= NN) return;

    const int beg = offs[n], end = offs[n + 1];
    const float ep = 1.0f + epsp[0];
    const size_t fo = (size_t)(lane << 1);

    float2 a0 = make_float2(0.f, 0.f), a1 = make_float2(0.f, 0.f);
    float2 a2 = make_float2(0.f, 0.f), a3 = make_float2(0.f, 0.f);
    int i = beg;
    for (; i + 3 < end; i += 4) {
        int s0 = esrc[i], s1 = esrc[i + 1], s2 = esrc[i + 2], s3 = esrc[i + 3];
        const float2 v0 = *(const float2*)(X + (size_t)s0 * HIDD + fo);
        const float2 v1 = *(const float2*)(X + (size_t)s1 * HIDD + fo);
        const float2 v2 = *(const float2*)(X + (size_t)s2 * HIDD + fo);
        const float2 v3 = *(const float2*)(X + (size_t)s3 * HIDD + fo);
        a0.x += v0.x; a0.y += v0.y;
        a1.x += v1.x; a1.y += v1.y;
        a2.x += v2.x; a2.y += v2.y;
        a3.x += v3.x; a3.y += v3.y;
    }
    for (; i < end; ++i) {
        int s = esrc[i];
        const float2 v = *(const float2*)(X + (size_t)s * HIDD + fo);
        a0.x += v.x; a0.y += v.y;
    }
    const float2 xv = *(const float2*)(X + (size_t)n * HIDD + fo);
    float ox = fmaf(ep, xv.x, (a0.x + a1.x) + (a2.x + a3.x));
    float oy = fmaf(ep, xv.y, (a0.y + a1.y) + (a2.y + a3.y));
    unsigned int lo = (unsigned short)f2bf(ox);
    unsigned int hi = (unsigned short)f2bf(oy);
    Ab[(size_t)n * 64 + lane] = lo | (hi << 16);
}

// ---------------------------------------------------------------------------
// MFMA GEMM1: Hb = bf16( Ab @ Wt^T + bias ), BN partials per block.
// Block 256 thr = 4 waves; 64 rows x 128 cols; wave w owns rows w*16..w*16+15.
__global__ __launch_bounds__(256) void gemm_stats_mfma(
    const short* __restrict__ Ab, const short* __restrict__ Wt,
    const float* __restrict__ bias, short* __restrict__ Hb,
    float* __restrict__ partial)
{
    __shared__ short As[64 * LDAS];
    __shared__ float sred[256];
    const int tid  = threadIdx.x;
    const int row0 = blockIdx.x * 64;

    // stage A tile: 1024 chunks of 8 bf16 (16 B), coalesced
    #pragma unroll
    for (int p = 0; p < 4; ++p) {
        int c  = p * 256 + tid;
        int r  = c >> 4, k8 = c & 15;
        int row = row0 + r;
        short8 v = {};
        if (row < NN) v = *(const short8*)(Ab + (size_t)row * 128 + k8 * 8);
        *(short8*)(&As[r * LDAS + k8 * 8]) = v;
    }
    sred[tid] = 0.f;
    __syncthreads();

    const int w  = tid >> 6;
    const int l  = tid & 63;
    const int cl = l & 15;
    const int koff = (l >> 4) * 8;
    const int arow = w * 16 + cl;

    short8 afr[4];
    #pragma unroll
    for (int kb = 0; kb < 4; ++kb)
        afr[kb] = *(const short8*)(&As[arow * LDAS + kb * 32 + koff]);

    #pragma unroll
    for (int n = 0; n < 8; ++n) {
        f32x4 acc = {0.f, 0.f, 0.f, 0.f};
        const short* wp = Wt + (size_t)(n * 16 + cl) * 128 + koff;
        #pragma unroll
        for (int kb = 0; kb < 4; ++kb) {
            short8 bfr = *(const short8*)(wp + kb * 32);
            acc = __builtin_amdgcn_mfma_f32_16x16x32_bf16(afr[kb], bfr, acc, 0, 0, 0);
        }
        const int col = n * 16 + cl;
        const float bcol = bias[col];
        float ps = 0.f, pq = 0.f;
        #pragma unroll
        for (int i = 0; i < 4; ++i) {
            int row = row0 + w * 16 + ((l >> 4) << 2) + i;
            if (row < NN) {
                float h = acc[i] + bcol;
                Hb[(size_t)row * 128 + col] = f2bf(h);
                ps += h; pq += h * h;
            }
        }
        ps += __shfl_xor(ps, 16); pq += __shfl_xor(pq, 16);
        ps += __shfl_xor(ps, 32); pq += __shfl_xor(pq, 32);
        if (l < 16) {
            atomicAdd(&sred[col], ps);
            atomicAdd(&sred[128 + col], pq);
        }
    }
    __syncthreads();
    partial[(size_t)blockIdx.x * 256 + tid] = sred[tid];
}

// ---------------------------------------------------------------------------
// Reduce per-block partials -> BN scale/shift.
__global__ __launch_bounds__(1024) void reduce_stats_kernel(
    const float* __restrict__ partial, const float* __restrict__ g,
    const float* __restrict__ bt, float* __restrict__ stats)
{
    __shared__ float buf[4][256];
    const int t  = threadIdx.x;
    const int c  = t & 255;
    const int ch = t >> 8;
    const int per = (NB_X + 3) / 4;
    const int b0 = ch * per;
    const int b1 = min(b0 + per, NB_X);

    float s = 0.f;
    #pragma unroll 8
    for (int b = b0; b < b1; ++b) s += partial[(size_t)b * 256 + c];
    buf[ch][c] = s;
    __syncthreads();

    if (t < 256) buf[0][t] = buf[0][t] + buf[1][t] + buf[2][t] + buf[3][t];
    __syncthreads();

    if (t < 128) {
        const float invN = 1.0f / (float)NN;
        float mu  = buf[0][t] * invN;
        float var = buf[0][128 + t] * invN - mu * mu;
        float sc  = g[t] * rsqrtf(var + 1e-5f);
        stats[256 + t] = sc;
        stats[384 + t] = bt[t] - mu * sc;
    }
}

// ---------------------------------------------------------------------------
// MFMA GEMM2: Y = relu_opt( relu(bn(Hb)) @ Wt^T + bias ), f32 output.
__global__ __launch_bounds__(256) void gemm_post_mfma(
    const short* __restrict__ Hb, const float* __restrict__ stats,
    const short* __restrict__ Wt, const float* __restrict__ bias,
    float* __restrict__ Y, int final_relu)
{
    __shared__ short As[64 * LDAS];
    const int tid  = threadIdx.x;
    const int row0 = blockIdx.x * 64;

    #pragma unroll
    for (int p = 0; p < 4; ++p) {
        int c  = p * 256 + tid;
        int r  = c >> 4, k8 = c & 15;
        int row = row0 + r;
        short8 v = {};
        if (row < NN) {
            short8 hv = *(const short8*)(Hb + (size_t)row * 128 + k8 * 8);
            #pragma unroll
            for (int j = 0; j < 8; ++j) {
                int k = k8 * 8 + j;
                float f = bf2f(hv[j]);
                f = fmaxf(fmaf(f, stats[256 + k], stats[384 + k]), 0.f);
                v[j] = f2bf(f);
            }
        }
        *(short8*)(&As[r * LDAS + k8 * 8]) = v;
    }
    __syncthreads();

    const int w  = tid >> 6;
    const int l  = tid & 63;
    const int cl = l & 15;
    const int koff = (l >> 4) * 8;
    const int arow = w * 16 + cl;

    short8 afr[4];
    #pragma unroll
    for (int kb = 0; kb < 4; ++kb)
        afr[kb] = *(const short8*)(&As[arow * LDAS + kb * 32 + koff]);

    #pragma unroll
    for (int n = 0; n < 8; ++n) {
        f32x4 acc = {0.f, 0.f, 0.f, 0.f};
        const short* wp = Wt + (size_t)(n * 16 + cl) * 128 + koff;
        #pragma unroll
        for (int kb = 0; kb < 4; ++kb) {
            short8 bfr = *(const short8*)(wp + kb * 32);
            acc = __builtin_amdgcn_mfma_f32_16x16x32_bf16(afr[kb], bfr, acc, 0, 0, 0);
        }
        const int col = n * 16 + cl;
        const float bcol = bias[col];
        #pragma unroll
        for (int i = 0; i < 4; ++i) {
            int row = row0 + w * 16 + ((l >> 4) << 2) + i;
            if (row < NN) {
                float h = acc[i] + bcol;
                if (final_relu) h = fmaxf(h, 0.f);
                Y[(size_t)row * 128 + col] = h;
            }
        }
    }
}

// ---------------------------------------------------------------------------
extern "C" void kernel_launch(void* const* d_in, const int* in_sizes, int n_in,
                              void* d_out, int out_size, void* d_ws, size_t ws_size,
                              hipStream_t stream)
{
    const float* x    = (const float*)d_in[0];
    const int*   src  = (const int*)  d_in[1];
    const int*   dst  = (const int*)  d_in[2];
    const float* eps1 = (const float*)d_in[3];
    const float* w1a  = (const float*)d_in[4];
    const float* b1a  = (const float*)d_in[5];
    const float* g1   = (const float*)d_in[6];
    const float* bt1  = (const float*)d_in[7];
    const float* w1b  = (const float*)d_in[8];
    const float* b1b  = (const float*)d_in[9];
    const float* eps2 = (const float*)d_in[10];
    const float* w2a  = (const float*)d_in[11];
    const float* b2a  = (const float*)d_in[12];
    const float* g2   = (const float*)d_in[13];
    const float* bt2  = (const float*)d_in[14];
    const float* w2b  = (const float*)d_in[15];
    const float* b2b  = (const float*)d_in[16];

    float* out = (float*)d_out;

    // workspace layout (all 16B-aligned by construction)
    short* Ab      = (short*)d_ws;                       // NN*128 bf16 = 25.6 MB
    short* Hb      = Ab + (size_t)NN * 128;              // 25.6 MB
    float* stats   = (float*)(Hb + (size_t)NN * 128);    // 512 f32
    float* partial = stats + 512;                        // NB_X*256 f32
    int*   offs    = (int*)(partial + (size_t)NB_X * 256);  // NN+4 (padded)
    int*   degcur  = offs + (NN + 4);                    // NN
    int*   esrc    = degcur + NN;                        // NE
    int*   scanned = esrc + NE;                          // NSB*1024
    int*   bsum    = scanned + NSB * 1024;               // 100 (padded)
    int*   bbase   = bsum + 100;                         // 100 (padded)
    short* wt      = (short*)(bbase + 100);              // 4*16384 bf16 = 128 KB

    const int edge_blocks   = NE / 256;                  // 6250
    const int gather_blocks = (NN * 64 + 255) / 256;     // 25000

    // ---- one-time prep ----
    convert_w_kernel<<<4, 256, 0, stream>>>(w1a, w1b, w2a, w2b, wt);
    hipMemsetAsync(degcur, 0, NN * sizeof(int), stream);
    count_kernel<<<edge_blocks, 256, 0, stream>>>(dst, degcur);
    scan1_kernel<<<NSB, 1024, 0, stream>>>(degcur, scanned, bsum);
    scan2_kernel<<<1, 128, 0, stream>>>(bsum, bbase, offs);
    scan3_kernel<<<NSB, 1024, 0, stream>>>(scanned, bbase, offs, degcur);
    fill_kernel<<<edge_blocks, 256, 0, stream>>>(src, dst, degcur, esrc);

    // ---- Layer 1 ----
    gather_kernel<<<gather_blocks, 256, 0, stream>>>(x, offs, esrc, eps1,
                                                     (unsigned int*)Ab);
    gemm_stats_mfma<<<NB_X, 256, 0, stream>>>(Ab, wt, b1a, Hb, partial);
    reduce_stats_kernel<<<1, 1024, 0, stream>>>(partial, g1, bt1, stats);
    gemm_post_mfma<<<NB_X, 256, 0, stream>>>(Hb, stats, wt + 16384, b1b, out, 1);

    // ---- Layer 2 (input = out) ----
    gather_kernel<<<gather_blocks, 256, 0, stream>>>(out, offs, esrc, eps2,
                                                     (unsigned int*)Ab);
    gemm_stats_mfma<<<NB_X, 256, 0, stream>>>(Ab, wt + 32768, b2a, Hb, partial);
    reduce_stats_kernel<<<1, 1024, 0, stream>>>(partial, g2, bt2, stats);
    gemm_post_mfma<<<NB_X, 256, 0, stream>>>(Hb, stats, wt + 49152, b2b, out, 0);
}